// Round 15
// baseline (175.069 us; speedup 1.0000x reference)
//
#include <hip/hip_runtime.h>

#define NN 16384
#define NE 262144
#define CAP 64               // slots per target; in-degree ~Poisson(16), P(>=64) ~ 1e-19

// ============================================================================
// 5 dispatches: zero -> scatter(tgt slots) -> layer1 -> layer2 -> poolfinal
// layer kernel: per-target T[9] register outer-product accumulation over
// in-edges (gathers 128B h-rows from a 2MB L2-resident table), then in-register
// transform (T,h[t]) -> agg via LDS-staged weights. No G table, no atomics.
// ============================================================================

__global__ __launch_bounds__(256) void zero_kernel(int* __restrict__ cnt,
                                                   float* __restrict__ pooled,
                                                   int* __restrict__ ticket)
{
    int i = blockIdx.x * blockDim.x + threadIdx.x;
    if (i < NN) cnt[i] = 0;
    if (i < 32) pooled[i] = 0.0f;
    if (i == 32) *ticket = 0;
}

// pair[t*CAP + idx] = {src, eid}; idx via atomic on cnt[t] (mean 16/target).
__global__ __launch_bounds__(256) void scatter_kernel(
    const int* __restrict__ src, const int* __restrict__ tgt,
    int* __restrict__ cnt, int2* __restrict__ pair)
{
    int i = blockIdx.x * blockDim.x + threadIdx.x;
    if (i < NE) {
        int t = tgt[i];
        int idx = atomicAdd(&cnt[t], 1);
        if (idx < CAP)
            pair[(size_t)t * CAP + idx] = make_int2(src[i], i);
    }
}

// ----------------------------------------------------------------------------
// layer kernel: one half-wave per target node (grid 2048x256 = 16384 halves).
// Phase 1 (edge loop): lane = input index i. T[s] += e[ed][s] * h[src][i],
//   T[8] += h[src][i]. h row = 128B coalesced load from 2MB table (L2-hot).
// Phase 2 (epilogue): lane = output index o.
//   agg[t][o] = b[o] + h[t].root[:,o] + sum_{s,i} T[s,i] * W[s][i][o]
//   with W (Wk|bk|root, 40KB) staged in LDS; T[s,i] via __shfl broadcast.
// ----------------------------------------------------------------------------
__global__ __launch_bounds__(256) void layer_kernel(
    const float* __restrict__ hin, int stride, int apply_relu,
    const float* __restrict__ efeat, const int2* __restrict__ pair,
    const int* __restrict__ cnt,
    const float* __restrict__ Wk, const float* __restrict__ bk,
    const float* __restrict__ root, const float* __restrict__ bvec,
    float* __restrict__ aggout)
{
    __shared__ float wlds[10 * 1024];          // [s][i][o], s: 0..7 Wk, 8 bk, 9 root
    for (int idx = threadIdx.x; idx < 8 * 1024; idx += 256)
        wlds[idx] = Wk[idx];
    for (int idx = threadIdx.x; idx < 1024; idx += 256) {
        wlds[8 * 1024 + idx] = bk[idx];
        wlds[9 * 1024 + idx] = root[idx];
    }
    __syncthreads();

    int lane = threadIdx.x & 63;
    int i    = lane & 31;                      // input idx (phase 1) / output idx (phase 2)
    int hb   = lane & 32;                      // half base for width-64 shfl
    int t    = blockIdx.x * 8 + (threadIdx.x >> 5);   // half-wave id = target

    float T[9] = {0.f, 0.f, 0.f, 0.f, 0.f, 0.f, 0.f, 0.f, 0.f};

    int n = cnt[t];
    if (n > CAP) n = CAP;
    const int2* ps = pair + (size_t)t * CAP;

    for (int j = 0; j < n; ++j) {
        int2 p = ps[j];
        float hv = hin[(size_t)p.x * stride + i];
        if (apply_relu) hv = fmaxf(hv, 0.0f);
        float ev = efeat[(size_t)p.y * 8 + (i & 7)];
#pragma unroll
        for (int s = 0; s < 8; ++s) {
            float es = __shfl(ev, hb | s, 64);
            T[s] = fmaf(es, hv, T[s]);
        }
        T[8] += hv;
    }

    // epilogue: in-register transform to output space
    float ht = hin[(size_t)t * stride + i];
    if (apply_relu) ht = fmaxf(ht, 0.0f);
    float acc = bvec[i];

#pragma unroll 4
    for (int ii = 0; ii < 32; ++ii) {
        float hbr = __shfl(ht, hb | ii, 64);
        acc = fmaf(hbr, wlds[9 * 1024 + ii * 32 + i], acc);
#pragma unroll
        for (int s = 0; s < 9; ++s) {
            float tbr = __shfl(T[s], hb | ii, 64);
            acc = fmaf(tbr, wlds[s * 1024 + ii * 32 + i], acc);
        }
    }

    aggout[(size_t)t * 32 + i] = acc;
}

// ----------------------------------------------------------------------------
// poolfinal: pooled[o] = sum_v relu(agg[v][o]); last block does the dense head.
// ----------------------------------------------------------------------------
__global__ __launch_bounds__(256) void poolfinal_kernel(
    const float* __restrict__ agg, const float* __restrict__ Wd,
    const float* __restrict__ bd, float* __restrict__ pooled,
    int* __restrict__ ticket, float* __restrict__ out)
{
    int gtid  = blockIdx.x * blockDim.x + threadIdx.x;
    int o     = gtid & 31;
    int row0  = gtid >> 5;
    int nrows = (gridDim.x * blockDim.x) >> 5;
    float sum = 0.0f;
    for (int v = row0; v < NN; v += nrows)
        sum += fmaxf(agg[(size_t)v * 32 + o], 0.0f);
    sum += __shfl_xor(sum, 32, 64);
    if ((threadIdx.x & 63) < 32) atomicAdd(pooled + o, sum);
    __threadfence();
    __syncthreads();
    __shared__ int last;
    if (threadIdx.x == 0)
        last = (atomicAdd(ticket, 1) == (int)gridDim.x - 1) ? 1 : 0;
    __syncthreads();
    if (last && threadIdx.x < 64) {
        float pv = 0.0f;
        if (threadIdx.x < 32)
            pv = atomicAdd(pooled + threadIdx.x, 0.0f) * Wd[threadIdx.x];
#pragma unroll
        for (int k = 32; k >= 1; k >>= 1) pv += __shfl_xor(pv, k, 64);
        if (threadIdx.x == 0) out[0] = fmaxf(pv + bd[0], 0.0f);
    }
}

// ============================================================================
extern "C" void kernel_launch(void* const* d_in, const int* in_sizes, int n_in,
                              void* d_out, int out_size, void* d_ws, size_t ws_size,
                              hipStream_t stream)
{
    const float* x     = (const float*)d_in[0];
    const int*   src   = (const int*)d_in[1];
    const int*   tgt   = (const int*)d_in[2];
    const float* e     = (const float*)d_in[3];
    const float* Wk1   = (const float*)d_in[4];
    const float* bk1   = (const float*)d_in[5];
    const float* root1 = (const float*)d_in[6];
    const float* b1    = (const float*)d_in[7];
    const float* Wk2   = (const float*)d_in[8];
    const float* bk2   = (const float*)d_in[9];
    const float* root2 = (const float*)d_in[10];
    const float* b2    = (const float*)d_in[11];
    const float* Wd    = (const float*)d_in[12];
    const float* bd    = (const float*)d_in[13];
    float* out = (float*)d_out;

    // workspace: agg1 (2MB) | agg2 (2MB) | pooled+ticket (256B) | cnt (64KB)
    //          | pair (16384*64*8 = 8MB)   — total ~12.1 MB
    char* ws = (char*)d_ws;
    size_t off = 0;
    float* agg1   = (float*)(ws + off); off += (size_t)NN * 32 * 4;
    float* agg2   = (float*)(ws + off); off += (size_t)NN * 32 * 4;
    float* pooled = (float*)(ws + off);
    int*   ticket = (int*)  (ws + off + 32 * 4); off += 256;
    int*   cnt    = (int*)  (ws + off); off += (size_t)NN * 4;
    int2*  pair   = (int2*) (ws + off); off += (size_t)NN * CAP * 8;

    zero_kernel<<<64, 256, 0, stream>>>(cnt, pooled, ticket);
    scatter_kernel<<<NE / 256, 256, 0, stream>>>(src, tgt, cnt, pair);

    // layer 1: h = x[:, :32] (stride 33)
    layer_kernel<<<2048, 256, 0, stream>>>(x, 33, 0, e, pair, cnt,
                                           Wk1, bk1, root1, b1, agg1);
    // layer 2: h = relu(agg1) (stride 32, relu on load)
    layer_kernel<<<2048, 256, 0, stream>>>(agg1, 32, 1, e, pair, cnt,
                                           Wk2, bk2, root2, b2, agg2);

    poolfinal_kernel<<<64, 256, 0, stream>>>(agg2, Wd, bd, pooled, ticket, out);
}